// Round 9
// baseline (140292.603 us; speedup 1.0000x reference)
//
#include <hip/hip_runtime.h>

#define TT 1000
#define HH 512
#define G4 2048
#define NGRP 8
#define SPG 16        // seqs per group
#define SLOTS 32      // blocks per group
#define HCB 16        // h-cols per block (64 gate cols)

typedef __attribute__((ext_vector_type(8))) short bf16x8;
typedef __attribute__((ext_vector_type(4))) float f32x4;
typedef __attribute__((ext_vector_type(4))) unsigned u32x4;

__device__ __forceinline__ float sigm(float v) { return 1.0f / (1.0f + __expf(-v)); }
__device__ __forceinline__ float tanh_fast(float v) { return 2.0f / (1.0f + __expf(-2.0f * v)) - 1.0f; }

__device__ __forceinline__ unsigned short bf16rne(float f) {
    unsigned u = __float_as_uint(f);
    return (unsigned short)((u + 0x7fffu + ((u >> 16) & 1u)) >> 16);
}

// 256 blocks x 256 thr, 1/CU (dyn-LDS pad). Fast path: groups = physical XCDs
// (claimed via s_getreg XCC_ID), exchange = self-tagged u32 words
// (bf16(h)<<16 | step_tag) stored sc0 (write-through to XCD L2) and read sc0
// (L1-bypass): no flags, no acks, one local-L2 hop. The mechanism is TESTED
// at startup; a global veto falls everyone back to the proven agent-scope
// flag protocol. ws: slab u32[2][128][512] (512K) | ctrl (513K) | fflag (516K).
__global__ __launch_bounds__(256, 1)
void lstm_xcd2(const float* __restrict__ x,     // [B][T][2]
               const float* __restrict__ wih,   // [2][4H]
               const float* __restrict__ whh,   // [H][4H]
               const float* __restrict__ bias,  // [4H]
               float* __restrict__ out,         // h [B][T][H] then c [B][T][H]
               float* ws)
{
    extern __shared__ char lds_pad[];   // 68 KB dynamic: forces 1 block/CU
    __shared__ short hsh[16 * 512];     // h(t) bf16, swizzled (16 KB)
    __shared__ unsigned info[2];

    const int bid  = blockIdx.x;
    const int tid  = threadIdx.x;
    const int wv   = tid >> 6;
    const int lane = tid & 63;
    const int col  = lane & 15;
    const int kb   = lane >> 4;            // k-subchunk / row-group
    const int q    = col & 3;              // gate id 0=f,1=i,2=o,3=g
    const int q1   = q & 1, q2 = q >> 1;
    const int cc   = col >> 2;
    const int rowSel = kb * 4 + q;         // owned seq row (0..15)

    unsigned* slab  = (unsigned*)ws;                        // u32[2][128][512]
    unsigned* ctrl  = (unsigned*)((char*)ws + 512 * 1024);
    unsigned* fflag = (unsigned*)((char*)ws + 516 * 1024);  // fallback flags

    for (int i = tid; i < 4096; i += 256) ((unsigned*)hsh)[i] = 0u;

    // ---- one-time claim + GLOBAL decision (bid 0 aggregates) ----
    if (tid == 0) {
        unsigned xcc;
        asm volatile("s_getreg_b32 %0, hwreg(20, 0, 32)" : "=s"(xcc));
        xcc &= 7u;
        unsigned slot = __hip_atomic_fetch_add(&ctrl[xcc * 16], 1u,
                            __ATOMIC_RELAXED, __HIP_MEMORY_SCOPE_AGENT);
        __hip_atomic_fetch_add(&ctrl[128], 1u, __ATOMIC_RELEASE, __HIP_MEMORY_SCOPE_AGENT);
        if (bid == 0) {
            long gd = 0;
            while (__hip_atomic_load(&ctrl[128], __ATOMIC_ACQUIRE,
                                     __HIP_MEMORY_SCOPE_AGENT) < 256u) {
                __builtin_amdgcn_s_sleep(2);
                if (++gd > 30000000L) break;
            }
            unsigned okv = 1u;
            for (int j = 0; j < 8; ++j)
                okv &= (__hip_atomic_load(&ctrl[j * 16], __ATOMIC_RELAXED,
                            __HIP_MEMORY_SCOPE_AGENT) == 32u) ? 1u : 0u;
            __hip_atomic_store(&ctrl[144], okv ? 1u : 2u,
                               __ATOMIC_RELEASE, __HIP_MEMORY_SCOPE_AGENT);
        }
        unsigned dv = 0; long gd = 0;
        for (;;) {
            dv = __hip_atomic_load(&ctrl[144], __ATOMIC_ACQUIRE, __HIP_MEMORY_SCOPE_AGENT);
            if (dv) break;
            __builtin_amdgcn_s_sleep(2);
            if (++gd > 30000000L) { dv = 2; break; }
        }
        info[0] = (xcc << 8) | (slot & 255u);
        info[1] = dv;
    }
    __syncthreads();

    unsigned dec = info[1];
    const int g_f = (int)(info[0] >> 8);
    const int s_f = (int)(info[0] & 255u);

    // ---- live test of the sc0 exchange mechanism; global veto on failure ----
    if (dec == 1) {
        const int bSf = g_f * SPG + rowSel;
        if (cc == 0) {
            u32x4 tw; tw.x = tw.y = tw.z = tw.w = 0xABCD7FFFu;
            unsigned* dst = slab + ((size_t)(128 + bSf)) * 512 + s_f * HCB + wv * 4;
            asm volatile("global_store_dwordx4 %0, %1, off sc0"
                         :: "v"(dst), "v"(tw) : "memory");
        }
        __syncthreads();
        const unsigned* base = slab + ((size_t)(128 + g_f * SPG)) * 512;
        unsigned pend = 0xFFu;
        long sw = 0;
        while (pend && sw < 300000) {
            ++sw;
            #pragma unroll
            for (int i = 0; i < 8; ++i) if (pend & (1u << i)) {
                u32x4 v;
                const unsigned* ap = base + (size_t)(i * 256 + tid) * 4;
                asm volatile("global_load_dwordx4 %0, %1, off sc0\n\ts_waitcnt vmcnt(0)"
                             : "=v"(v) : "v"(ap) : "memory");
                if ((((v.x ^ 0x7FFFu) | (v.y ^ 0x7FFFu) |
                      (v.z ^ 0x7FFFu) | (v.w ^ 0x7FFFu)) & 0xFFFFu) == 0u)
                    pend &= ~(1u << i);
            }
            if (pend) __builtin_amdgcn_s_sleep(1);
        }
        int allok = __syncthreads_and(pend == 0u);
        if (tid == 0) {
            if (!allok)
                __hip_atomic_fetch_or(&ctrl[160], 1u, __ATOMIC_RELAXED, __HIP_MEMORY_SCOPE_AGENT);
            __hip_atomic_fetch_add(&ctrl[176], 1u, __ATOMIC_RELEASE, __HIP_MEMORY_SCOPE_AGENT);
            long gd = 0;
            while (__hip_atomic_load(&ctrl[176], __ATOMIC_ACQUIRE,
                                     __HIP_MEMORY_SCOPE_AGENT) < 256u) {
                __builtin_amdgcn_s_sleep(2);
                if (++gd > 30000000L) break;
            }
            unsigned veto = __hip_atomic_load(&ctrl[160], __ATOMIC_RELAXED,
                                              __HIP_MEMORY_SCOPE_AGENT);
            info[1] = veto ? 2u : 1u;
        }
        __syncthreads();
        dec = info[1];
    }

    const int fast = (dec == 1);
    const int g    = fast ? g_f : (bid & 7);
    const int slot = fast ? s_f : (bid >> 3);

    const int hl   = wv * 4 + cc;                 // block h-col 0..15
    const int gc   = q * 512 + slot * HCB + hl;   // global gate col
    const int bSel = g * SPG + rowSel;            // global batch index

    // ---- one-time: W_hh fragments into registers (64 VGPR) ----
    bf16x8 breg[16];
    #pragma unroll
    for (int kt = 0; kt < 16; ++kt) {
        bf16x8 f;
        #pragma unroll
        for (int j = 0; j < 8; ++j) {
            int k = kt * 32 + kb * 8 + j;
            f[j] = (short)bf16rne(whh[(size_t)k * G4 + gc]);
        }
        breg[kt] = f;
    }
    float wA[4], wB[4], bb[4];
    #pragma unroll
    for (int j = 0; j < 4; ++j) {
        int gcj = j * 512 + slot * HCB + hl;
        wA[j] = wih[gcj]; wB[j] = wih[G4 + gcj]; bb[j] = bias[gcj];
    }

    const int arow = col;
    const int asw  = (arow & 7) << 3;
    const short* aBase = hsh + arow * 512;

    __syncthreads();

    float cst = 0.0f;
    const size_t OSZ = (size_t)128 * TT * HH;
    const float* xp = x + (size_t)bSel * TT * 2;
    float2 xv = *(const float2*)(xp);

    for (int t = 0; t < TT; ++t) {
        // ---- gates = h @ W_hh (K=512, MFMA, 2 acc chains) ----
        f32x4 acc0 = {0.f, 0.f, 0.f, 0.f};
        f32x4 acc1 = {0.f, 0.f, 0.f, 0.f};
        #pragma unroll
        for (int kt = 0; kt < 16; kt += 2) {
            int ka = (kt * 32 + kb * 8);
            bf16x8 a0 = *(const bf16x8*)(aBase + (ka ^ asw));
            acc0 = __builtin_amdgcn_mfma_f32_16x16x32_bf16(a0, breg[kt], acc0, 0, 0, 0);
            int kc = ((kt + 1) * 32 + kb * 8);
            bf16x8 a1 = *(const bf16x8*)(aBase + (kc ^ asw));
            acc1 = __builtin_amdgcn_mfma_f32_16x16x32_bf16(a1, breg[kt + 1], acc1, 0, 0, 0);
        }
        float v0 = acc0[0] + acc1[0], v1 = acc0[1] + acc1[1];
        float v2 = acc0[2] + acc1[2], v3 = acc0[3] + acc1[3];

        // ---- quad butterfly: lane ends with all 4 gates of row rowSel ----
        float vq = q2 ? (q1 ? v3 : v2) : (q1 ? v1 : v0);
        float s1 = q2 ? (q1 ? v2 : v3) : (q1 ? v0 : v1);
        float s2 = q2 ? (q1 ? v1 : v0) : (q1 ? v3 : v2);
        float s3 = q2 ? (q1 ? v0 : v1) : (q1 ? v2 : v3);
        float g1 = __shfl_xor(s1, 1);
        float g2 = __shfl_xor(s2, 2);
        float g3 = __shfl_xor(s3, 3);

        float fv = q2 ? (q1 ? g3 : g2) : (q1 ? g1 : vq);
        float iv = q2 ? (q1 ? g2 : g3) : (q1 ? vq : g1);
        float ov = q2 ? (q1 ? g1 : vq) : (q1 ? g3 : g2);
        float gv = q2 ? (q1 ? vq : g1) : (q1 ? g2 : g3);

        fv += xv.x * wA[0] + xv.y * wB[0] + bb[0];
        iv += xv.x * wA[1] + xv.y * wB[1] + bb[1];
        ov += xv.x * wA[2] + xv.y * wB[2] + bb[2];
        gv += xv.x * wA[3] + xv.y * wB[3] + bb[3];

        float c1 = sigm(fv) * cst + sigm(iv) * tanh_fast(gv);
        float h1 = sigm(ov) * tanh_fast(c1);
        cst = c1;

        // h pack shuffles first (producer store ASAP), c shuffles after
        float hp1 = __shfl_xor(h1, 4);
        float hp2 = __shfl_xor(h1, 8);
        float hp3 = __shfl_xor(hp1, 8);

        const unsigned tag = (unsigned)(t + 1);
        const int phase = (t + 1) & 1;

        if (t + 1 < TT) {
            if (cc == 0) {
                u32x4 w;
                w.x = ((unsigned)bf16rne(h1)  << 16) | tag;
                w.y = ((unsigned)bf16rne(hp1) << 16) | tag;
                w.z = ((unsigned)bf16rne(hp2) << 16) | tag;
                w.w = ((unsigned)bf16rne(hp3) << 16) | tag;
                unsigned* dst = slab + ((size_t)(phase * 128 + bSel)) * 512
                              + slot * HCB + wv * 4;
                if (fast) {
                    asm volatile("global_store_dwordx4 %0, %1, off sc0"
                                 :: "v"(dst), "v"(w) : "memory");
                } else {
                    unsigned long long w0 = (unsigned long long)w.x
                                          | ((unsigned long long)w.y << 32);
                    unsigned long long w1 = (unsigned long long)w.z
                                          | ((unsigned long long)w.w << 32);
                    __hip_atomic_store((unsigned long long*)dst, w0,
                                       __ATOMIC_RELAXED, __HIP_MEMORY_SCOPE_AGENT);
                    __hip_atomic_store((unsigned long long*)dst + 1, w1,
                                       __ATOMIC_RELAXED, __HIP_MEMORY_SCOPE_AGENT);
                }
            }
        }

        float cp1 = __shfl_xor(c1, 4);
        float cp2 = __shfl_xor(c1, 8);
        float cp3 = __shfl_xor(cp1, 8);

        if (t + 1 < TT) {
            if (!fast) {
                asm volatile("s_waitcnt vmcnt(0)" ::: "memory");
            }
            __syncthreads();   // all hsh reads of this step done
            if (!fast && tid == 0)
                __hip_atomic_store(&fflag[(g * SLOTS + slot) * 16], tag,
                                   __ATOMIC_RELAXED, __HIP_MEMORY_SCOPE_AGENT);

            xv = *(const float2*)(xp + 2 * (t + 1));   // prefetch x(t+1)

            if (fast) {
                // ---- tagged sc0 sweep of the group slab (32 KB, local L2) ----
                const unsigned* base = slab + ((size_t)(phase * 128 + g * SPG)) * 512;
                u32x4 v0r, v1r, v2r, v3r, v4r, v5r, v6r, v7r;
                #define ISSUE(vv, i) asm volatile("global_load_dwordx4 %0, %1, off sc0" \
                    : "=v"(vv) : "v"(base + (size_t)((i) * 256 + tid) * 4))
                ISSUE(v0r, 0); ISSUE(v1r, 1); ISSUE(v2r, 2); ISSUE(v3r, 3);
                ISSUE(v4r, 4); ISSUE(v5r, 5); ISSUE(v6r, 6); ISSUE(v7r, 7);
                #undef ISSUE
                asm volatile("s_waitcnt vmcnt(0)"
                    : "+v"(v0r), "+v"(v1r), "+v"(v2r), "+v"(v3r),
                      "+v"(v4r), "+v"(v5r), "+v"(v6r), "+v"(v7r) :: "memory");
                u32x4 vals[8] = {v0r, v1r, v2r, v3r, v4r, v5r, v6r, v7r};

                unsigned pend = 0u;
                #pragma unroll
                for (int i = 0; i < 8; ++i) {
                    u32x4 v = vals[i];
                    if ((((v.x ^ tag) | (v.y ^ tag) | (v.z ^ tag) | (v.w ^ tag))
                         & 0xFFFFu) == 0u) {
                        int idx4 = i * 256 + tid;
                        int seq  = idx4 >> 7;
                        int c0   = (idx4 & 127) * 4;
                        unsigned lo = (v.x >> 16) | (v.y & 0xFFFF0000u);
                        unsigned hi = (v.z >> 16) | (v.w & 0xFFFF0000u);
                        *(unsigned long long*)(hsh + seq * 512 + (c0 ^ ((seq & 7) << 3)))
                            = (unsigned long long)lo | ((unsigned long long)hi << 32);
                    } else {
                        pend |= (1u << i);
                    }
                }
                long gd = 0;
                while (pend) {
                    #pragma unroll
                    for (int i = 0; i < 8; ++i) if (pend & (1u << i)) {
                        u32x4 v;
                        const unsigned* ap = base + (size_t)(i * 256 + tid) * 4;
                        asm volatile("global_load_dwordx4 %0, %1, off sc0\n\ts_waitcnt vmcnt(0)"
                                     : "=v"(v) : "v"(ap) : "memory");
                        if ((((v.x ^ tag) | (v.y ^ tag) | (v.z ^ tag) | (v.w ^ tag))
                             & 0xFFFFu) == 0u) {
                            int idx4 = i * 256 + tid;
                            int seq  = idx4 >> 7;
                            int c0   = (idx4 & 127) * 4;
                            unsigned lo = (v.x >> 16) | (v.y & 0xFFFF0000u);
                            unsigned hi = (v.z >> 16) | (v.w & 0xFFFF0000u);
                            *(unsigned long long*)(hsh + seq * 512 + (c0 ^ ((seq & 7) << 3)))
                                = (unsigned long long)lo | ((unsigned long long)hi << 32);
                            pend &= ~(1u << i);
                        }
                    }
                    if (pend) {
                        __builtin_amdgcn_s_sleep(1);
                        if (++gd > 500000L) break;   // anti-hang escape
                    }
                }
            } else {
                // ---- fallback: proven agent-scope flag protocol ----
                long gd = 0;
                for (;;) {
                    unsigned fl = (lane < SLOTS)
                        ? __hip_atomic_load(&fflag[(g * SLOTS + lane) * 16],
                                            __ATOMIC_RELAXED, __HIP_MEMORY_SCOPE_AGENT)
                        : tag;
                    if (__all(fl >= tag)) break;
                    __builtin_amdgcn_s_sleep(1);
                    if (++gd > 5000000L) break;
                }
                const unsigned long long* b64 = (const unsigned long long*)
                    (slab + ((size_t)(phase * 128 + g * SPG)) * 512);
                #pragma unroll
                for (int i = 0; i < 16; ++i) {
                    int idx = i * 256 + tid;
                    unsigned long long d = __hip_atomic_load(b64 + idx,
                            __ATOMIC_RELAXED, __HIP_MEMORY_SCOPE_AGENT);
                    int seq = idx >> 8;              // 256 u64 per 512-u32 row
                    int c0  = (idx & 255) * 2;
                    unsigned pk = (unsigned)((d >> 16) & 0xFFFFu)
                                | (unsigned)((d >> 32) & 0xFFFF0000u);
                    *(unsigned*)(hsh + seq * 512 + (c0 ^ ((seq & 7) << 3))) = pk;
                }
            }

            // out stores: fire-and-forget, acks overlap next compute
            if (cc == 0) {
                size_t oidx = ((size_t)bSel * TT + t) * HH + slot * HCB + wv * 4;
                float4 hq = {h1, hp1, hp2, hp3};
                float4 cq = {c1, cp1, cp2, cp3};
                *(float4*)(out + oidx) = hq;
                *(float4*)(out + OSZ + oidx) = cq;
            }
            __syncthreads();
        } else {
            if (cc == 0) {
                size_t oidx = ((size_t)bSel * TT + t) * HH + slot * HCB + wv * 4;
                float4 hq = {h1, hp1, hp2, hp3};
                float4 cq = {c1, cp1, cp2, cp3};
                *(float4*)(out + oidx) = hq;
                *(float4*)(out + OSZ + oidx) = cq;
            }
        }
    }
}

extern "C" void kernel_launch(void* const* d_in, const int* in_sizes, int n_in,
                              void* d_out, int out_size, void* d_ws, size_t ws_size,
                              hipStream_t stream) {
    const float* x    = (const float*)d_in[0];
    const float* wih  = (const float*)d_in[1];
    const float* whh  = (const float*)d_in[2];
    const float* bias = (const float*)d_in[3];
    float* out = (float*)d_out;
    float* ws  = (float*)d_ws;

    // zero slab tags + control + fallback flags every launch (graph replay safe)
    hipMemsetAsync(d_ws, 0, 532 * 1024, stream);

    dim3 grid(256), block(256);
    hipLaunchKernelGGL(lstm_xcd2, grid, block, 68 * 1024, stream,
                       x, wih, whh, bias, out, ws);
}

// Round 10
// 4574.358 us; speedup vs baseline: 30.6694x; 30.6694x over previous
//
#include <hip/hip_runtime.h>

#define TT 1000
#define HH 512
#define G4 2048
#define NGRP 8
#define SPG 16        // seqs per group
#define SLOTS 32      // blocks per group
#define HCB 16        // h-cols per block (64 gate cols)

typedef __attribute__((ext_vector_type(8))) short bf16x8;
typedef __attribute__((ext_vector_type(4))) float f32x4;

__device__ __forceinline__ float sigm(float v) { return 1.0f / (1.0f + __expf(-v)); }
__device__ __forceinline__ float tanh_fast(float v) { return 2.0f / (1.0f + __expf(-2.0f * v)) - 1.0f; }

__device__ __forceinline__ unsigned short bf16rne(float f) {
    unsigned u = __float_as_uint(f);
    return (unsigned short)((u + 0x7fffu + ((u >> 16) & 1u)) >> 16);
}

// 256 blocks x 256 thr (1/CU). group g = bid&7 owns seqs [g*16,+16);
// slot = bid>>3 owns h-cols [slot*16,+16) -> 64 gate cols. W_hh in VGPRs.
// Exchange: IN-BAND TAGGED u64s. h in [-1,1] => bf16 bit14 is always 0, so
// the 4 bf16 of each u64 donate 4 free bits = a mod-16 step tag embedded at
// zero byte cost. Producers fire-and-forget (agent relaxed, no ack, no flag);
// consumers run BATCHED 8-load sweeps (one vmcnt per round) with selective
// retry. Per-location coherence bounds staleness to tag-mismatched previous
// generation -> stale data is never accepted, only retried.
__global__ __launch_bounds__(256, 1)
void lstm_ibt(const float* __restrict__ x,     // [B][T][2]
              const float* __restrict__ wih,   // [2][4H]
              const float* __restrict__ whh,   // [H][4H]
              const float* __restrict__ bias,  // [4H]
              float* __restrict__ out,         // h [B][T][H] then c [B][T][H]
              float* ws)
{
    __shared__ short hsh[16 * 512];    // h(t) bf16, swizzled (16 KB)

    const int bid  = blockIdx.x;
    const int g    = bid & (NGRP - 1);
    const int slot = bid >> 3;
    const int tid  = threadIdx.x;
    const int wv   = tid >> 6;
    const int lane = tid & 63;
    const int col  = lane & 15;
    const int kb   = lane >> 4;            // k-subchunk / row-group
    const int q    = col & 3;              // gate id 0=f,1=i,2=o,3=g
    const int q1   = q & 1, q2 = q >> 1;
    const int cc   = col >> 2;
    const int hl   = wv * 4 + cc;          // block h-col 0..15
    const int gc   = q * 512 + slot * HCB + hl;   // global gate col
    const int rowSel = kb * 4 + q;         // this lane's owned seq row
    const int bSel   = g * SPG + rowSel;   // global batch index

    // slab: u64[2][128][128]  (2 phases x 128 seqs x 512 bf16)
    unsigned long long* slab = (unsigned long long*)ws;
    const unsigned long long TAGM = 0x4000400040004000ULL;

    // zero hsh (t=0 state)
    for (int i = tid; i < 4096; i += 256) ((unsigned*)hsh)[i] = 0u;

    // ---- one-time: W_hh fragments straight into registers (64 VGPR) ----
    bf16x8 breg[16];
    #pragma unroll
    for (int kt = 0; kt < 16; ++kt) {
        bf16x8 f;
        #pragma unroll
        for (int j = 0; j < 8; ++j) {
            int k = kt * 32 + kb * 8 + j;
            f[j] = (short)bf16rne(whh[(size_t)k * G4 + gc]);
        }
        breg[kt] = f;
    }

    float wA[4], wB[4], bb[4];
    #pragma unroll
    for (int j = 0; j < 4; ++j) {
        int gcj = j * 512 + slot * HCB + hl;
        wA[j] = wih[gcj]; wB[j] = wih[G4 + gcj]; bb[j] = bias[gcj];
    }

    const int arow = col;
    const int asw  = (arow & 7) << 3;
    const short* aBase = hsh + arow * 512;

    __syncthreads();

    float cst = 0.0f;
    const size_t OSZ = (size_t)128 * TT * HH;
    const float* xp = x + (size_t)bSel * TT * 2;
    float2 xv = *(const float2*)(xp);      // x(0) prefetched

    for (int t = 0; t < TT; ++t) {
        // ---- gates = h @ W_hh (K=512, MFMA, 2 acc chains) ----
        f32x4 acc0 = {0.f, 0.f, 0.f, 0.f};
        f32x4 acc1 = {0.f, 0.f, 0.f, 0.f};
        #pragma unroll
        for (int kt = 0; kt < 16; kt += 2) {
            int ka = (kt * 32 + kb * 8);
            bf16x8 a0 = *(const bf16x8*)(aBase + (ka ^ asw));
            acc0 = __builtin_amdgcn_mfma_f32_16x16x32_bf16(a0, breg[kt], acc0, 0, 0, 0);
            int kc = ((kt + 1) * 32 + kb * 8);
            bf16x8 a1 = *(const bf16x8*)(aBase + (kc ^ asw));
            acc1 = __builtin_amdgcn_mfma_f32_16x16x32_bf16(a1, breg[kt + 1], acc1, 0, 0, 0);
        }
        float v0 = acc0[0] + acc1[0], v1 = acc0[1] + acc1[1];
        float v2 = acc0[2] + acc1[2], v3 = acc0[3] + acc1[3];

        // ---- quad butterfly: lane ends with all 4 gates of row rowSel ----
        float vq = q2 ? (q1 ? v3 : v2) : (q1 ? v1 : v0);
        float s1 = q2 ? (q1 ? v2 : v3) : (q1 ? v0 : v1);
        float s2 = q2 ? (q1 ? v1 : v0) : (q1 ? v3 : v2);
        float s3 = q2 ? (q1 ? v0 : v1) : (q1 ? v2 : v3);
        float g1 = __shfl_xor(s1, 1);
        float g2 = __shfl_xor(s2, 2);
        float g3 = __shfl_xor(s3, 3);

        float fv = q2 ? (q1 ? g3 : g2) : (q1 ? g1 : vq);
        float iv = q2 ? (q1 ? g2 : g3) : (q1 ? vq : g1);
        float ov = q2 ? (q1 ? g1 : vq) : (q1 ? g3 : g2);
        float gv = q2 ? (q1 ? vq : g1) : (q1 ? g2 : g3);

        fv += xv.x * wA[0] + xv.y * wB[0] + bb[0];
        iv += xv.x * wA[1] + xv.y * wB[1] + bb[1];
        ov += xv.x * wA[2] + xv.y * wB[2] + bb[2];
        gv += xv.x * wA[3] + xv.y * wB[3] + bb[3];

        float c1 = sigm(fv) * cst + sigm(iv) * tanh_fast(gv);
        float h1 = sigm(ov) * tanh_fast(c1);
        cst = c1;

        // ---- pack h via shuffles; producer store issues ASAP ----
        float hp1 = __shfl_xor(h1, 4);
        float hp2 = __shfl_xor(h1, 8);
        float hp3 = __shfl_xor(hp1, 8);

        const unsigned tag  = (unsigned)(t + 1);
        const unsigned tag4 = tag & 15u;
        const int phase = (t + 1) & 1;

        if (t + 1 < TT && cc == 0) {
            // 4 bf16 (bit14 == 0 guaranteed for |h|<=1) + in-band mod-16 tag
            unsigned long long w =
                  (unsigned long long)bf16rne(h1)
                | ((unsigned long long)bf16rne(hp1) << 16)
                | ((unsigned long long)bf16rne(hp2) << 32)
                | ((unsigned long long)bf16rne(hp3) << 48);
            w |= ((unsigned long long)(tag4 & 1u)        << 14)
               | ((unsigned long long)((tag4 >> 1) & 1u) << 30)
               | ((unsigned long long)((tag4 >> 2) & 1u) << 46)
               | ((unsigned long long)((tag4 >> 3) & 1u) << 62);
            unsigned long long* dst = slab
                + ((size_t)(phase * 128 + bSel)) * 128 + slot * 4 + wv;
            __hip_atomic_store(dst, w, __ATOMIC_RELAXED, __HIP_MEMORY_SCOPE_AGENT);
        }

        float cp1 = __shfl_xor(c1, 4);
        float cp2 = __shfl_xor(c1, 8);
        float cp3 = __shfl_xor(cp1, 8);

        // ---- out flush from registers (fire-and-forget HBM stores) ----
        if (cc == 0) {
            size_t oidx = ((size_t)bSel * TT + t) * HH + slot * HCB + wv * 4;
            float4 hq = {h1, hp1, hp2, hp3};
            float4 cq = {c1, cp1, cp2, cp3};
            *(float4*)(out + oidx) = hq;
            *(float4*)(out + OSZ + oidx) = cq;
        }

        if (t + 1 < TT) {
            xv = *(const float2*)(xp + 2 * (t + 1));   // prefetch x(t+1)

            __syncthreads();   // all hsh reads of this step done

            // expected tag-bit pattern for this step
            const unsigned long long expp =
                  ((unsigned long long)(tag4 & 1u)        << 14)
                | ((unsigned long long)((tag4 >> 1) & 1u) << 30)
                | ((unsigned long long)((tag4 >> 2) & 1u) << 46)
                | ((unsigned long long)((tag4 >> 3) & 1u) << 62);

            const unsigned long long* src = slab
                + ((size_t)(phase * 128 + g * SPG)) * 128;
            const unsigned long long* a0p = src + 0 * 256 + tid;
            const unsigned long long* a1p = src + 1 * 256 + tid;
            const unsigned long long* a2p = src + 2 * 256 + tid;
            const unsigned long long* a3p = src + 3 * 256 + tid;
            const unsigned long long* a4p = src + 4 * 256 + tid;
            const unsigned long long* a5p = src + 5 * 256 + tid;
            const unsigned long long* a6p = src + 6 * 256 + tid;
            const unsigned long long* a7p = src + 7 * 256 + tid;

            unsigned pend = 0xFFu;
            long gd = 0;
            while (pend) {
                unsigned long long v0r, v1r, v2r, v3r, v4r, v5r, v6r, v7r;
                // batched sweep: 8 loads in flight, ONE waitcnt per round
                asm volatile(
                    "global_load_dwordx2 %0, %8, off sc0 sc1\n\t"
                    "global_load_dwordx2 %1, %9, off sc0 sc1\n\t"
                    "global_load_dwordx2 %2, %10, off sc0 sc1\n\t"
                    "global_load_dwordx2 %3, %11, off sc0 sc1\n\t"
                    "global_load_dwordx2 %4, %12, off sc0 sc1\n\t"
                    "global_load_dwordx2 %5, %13, off sc0 sc1\n\t"
                    "global_load_dwordx2 %6, %14, off sc0 sc1\n\t"
                    "global_load_dwordx2 %7, %15, off sc0 sc1\n\t"
                    "s_waitcnt vmcnt(0)"
                    : "=&v"(v0r), "=&v"(v1r), "=&v"(v2r), "=&v"(v3r),
                      "=&v"(v4r), "=&v"(v5r), "=&v"(v6r), "=&v"(v7r)
                    : "v"(a0p), "v"(a1p), "v"(a2p), "v"(a3p),
                      "v"(a4p), "v"(a5p), "v"(a6p), "v"(a7p)
                    : "memory");
                unsigned long long vals[8] = {v0r, v1r, v2r, v3r, v4r, v5r, v6r, v7r};
                #pragma unroll
                for (int i = 0; i < 8; ++i) {
                    if ((pend >> i) & 1u) {
                        if ((vals[i] & TAGM) == expp) {
                            int idx = i * 256 + tid;
                            int seq = idx >> 7;              // 128 u64 per row
                            int k0  = (idx & 127) << 2;
                            *(unsigned long long*)
                                (hsh + seq * 512 + (k0 ^ ((seq & 7) << 3)))
                                = vals[i] & ~TAGM;
                            pend &= ~(1u << i);
                        }
                    }
                }
                if (pend) {
                    __builtin_amdgcn_s_sleep(1);
                    if (++gd > 1000000L) break;   // anti-hang escape
                }
            }

            __syncthreads();
        }
    }
}

extern "C" void kernel_launch(void* const* d_in, const int* in_sizes, int n_in,
                              void* d_out, int out_size, void* d_ws, size_t ws_size,
                              hipStream_t stream) {
    const float* x    = (const float*)d_in[0];
    const float* wih  = (const float*)d_in[1];
    const float* whh  = (const float*)d_in[2];
    const float* bias = (const float*)d_in[3];
    float* out = (float*)d_out;
    float* ws  = (float*)d_ws;

    // zero the tagged slab every launch (tag bits invalid; graph replay safe)
    hipMemsetAsync(d_ws, 0, 2 * 128 * 512 * sizeof(short), stream);

    dim3 grid(NGRP * SLOTS), block(256);
    hipLaunchKernelGGL(lstm_ibt, grid, block, 0, stream, x, wih, whh, bias, out, ws);
}

// Round 11
// 3027.601 us; speedup vs baseline: 46.3379x; 1.5109x over previous
//
#include <hip/hip_runtime.h>

#define TT 1000
#define HH 512
#define G4 2048
#define NG 32         // groups
#define SLOTS 8       // blocks per group
#define SPG 4         // seqs per group
#define HCBLK 64      // h-cols per block

typedef __attribute__((ext_vector_type(8))) short bf16x8;
typedef __attribute__((ext_vector_type(4))) float f32x4;

__device__ __forceinline__ float sigm(float v) { return 1.0f / (1.0f + __expf(-v)); }
__device__ __forceinline__ float tanh_fast(float v) { return 2.0f / (1.0f + __expf(-2.0f * v)) - 1.0f; }

__device__ __forceinline__ unsigned short bf16rne(float f) {
    unsigned u = __float_as_uint(f);
    return (unsigned short)((u + 0x7fffu + ((u >> 16) & 1u)) >> 16);
}

// 256 blocks x 512 thr (8 waves, 1/CU). group g = bid&31 owns seqs [g*4,+4);
// slot = bid>>5 owns h-cols [slot*64,+64). Group members are bids == g mod 32
// -> same XCD under round-robin dispatch. Sync degree is 8 (was 32): 8 flag
// lines to poll, 4KB slab to sweep (1 u64/thread), max-of-8 stragglers.
// W_hh slice in VGPRs (128/lane, 2 tiles of 16 cols x K=512 per wave).
// MFMA runs M=16 with 12 zero rows (compute ~2% of step; latency rules).
// Exchange protocol = proven R4/R5 relaxed agent-scope flag protocol.
__global__ __launch_bounds__(512, 1)
void lstm_d8(const float* __restrict__ x,     // [B][T][2]
             const float* __restrict__ wih,   // [2][4H]
             const float* __restrict__ whh,   // [H][4H]
             const float* __restrict__ bias,  // [4H]
             float* __restrict__ out,         // h [B][T][H] then c [B][T][H]
             float* ws)
{
    __shared__ short hsh[16 * 512];    // h(t) bf16, swizzled; rows 4..15 stay 0

    const int bid  = blockIdx.x;
    const int g    = bid & (NG - 1);
    const int slot = bid >> 5;
    const int tid  = threadIdx.x;
    const int wv   = tid >> 6;             // 0..7
    const int lane = tid & 63;
    const int col  = lane & 15;
    const int kb   = lane >> 4;            // 0..3 (k-subchunk / row-group)
    const int q    = col & 3;              // gate id 0=f,1=i,2=o,3=g
    const int q1   = q & 1, q2 = q >> 1;
    const int cc   = col >> 2;             // within-tile h-col 0..3
    const int rowSel = kb * 4 + q;         // MFMA row; valid rows are 0..3 (kb==0)
    const int row4   = rowSel & 3;
    const int bSel   = g * SPG + row4;     // global batch index (safe clamp)
    const int hc0    = slot * HCBLK + wv * 8 + cc;       // tile0 h-col
    const int hc1    = hc0 + 4;                          // tile1 h-col

    // slab u64[2][128][128] = 256 KB ; flags at +256 KB: [32][8] lines 64B apart
    unsigned long long* slab = (unsigned long long*)ws;
    unsigned* flags = (unsigned*)((char*)ws + 256 * 1024);

    // zero hsh (t=0 state; rows 4..15 remain zero forever)
    for (int i = tid; i < 4096; i += 512) ((unsigned*)hsh)[i] = 0u;

    // ---- one-time: W_hh fragments into registers (2 tiles x 64 VGPR) ----
    const int gc0 = q * 512 + hc0;
    const int gc1 = q * 512 + hc1;
    bf16x8 breg0[16], breg1[16];
    #pragma unroll
    for (int kt = 0; kt < 16; ++kt) {
        bf16x8 f0, f1;
        #pragma unroll
        for (int j = 0; j < 8; ++j) {
            int k = kt * 32 + kb * 8 + j;
            f0[j] = (short)bf16rne(whh[(size_t)k * G4 + gc0]);
            f1[j] = (short)bf16rne(whh[(size_t)k * G4 + gc1]);
        }
        breg0[kt] = f0;
        breg1[kt] = f1;
    }

    // per-lane gate constants for both tiles (gate j at this lane's h-col)
    float wA0[4], wB0[4], bb0[4], wA1[4], wB1[4], bb1[4];
    #pragma unroll
    for (int j = 0; j < 4; ++j) {
        int a0 = j * 512 + hc0, a1 = j * 512 + hc1;
        wA0[j] = wih[a0]; wB0[j] = wih[G4 + a0]; bb0[j] = bias[a0];
        wA1[j] = wih[a1]; wB1[j] = wih[G4 + a1]; bb1[j] = bias[a1];
    }

    const int arow = col;
    const int asw  = (arow & 7) << 3;
    const short* aBase = hsh + arow * 512;

    __syncthreads();

    float cst0 = 0.0f, cst1 = 0.0f;
    const size_t OSZ = (size_t)128 * TT * HH;
    const float* xp = x + (size_t)bSel * TT * 2;
    float2 xv = *(const float2*)(xp);      // x(0) prefetched

    for (int t = 0; t < TT; ++t) {
        // ---- gates = h @ W_hh (K=512, one shared A-frag, two B-tiles) ----
        f32x4 acc0 = {0.f, 0.f, 0.f, 0.f};
        f32x4 acc1 = {0.f, 0.f, 0.f, 0.f};
        #pragma unroll
        for (int kt = 0; kt < 16; ++kt) {
            int ka = kt * 32 + kb * 8;
            bf16x8 a = *(const bf16x8*)(aBase + (ka ^ asw));
            acc0 = __builtin_amdgcn_mfma_f32_16x16x32_bf16(a, breg0[kt], acc0, 0, 0, 0);
            acc1 = __builtin_amdgcn_mfma_f32_16x16x32_bf16(a, breg1[kt], acc1, 0, 0, 0);
        }

        // ---- tile 0: quad butterfly + gate math ----
        float h1a, c1a;
        {
            float v0 = acc0[0], v1 = acc0[1], v2 = acc0[2], v3 = acc0[3];
            float vq = q2 ? (q1 ? v3 : v2) : (q1 ? v1 : v0);
            float s1 = q2 ? (q1 ? v2 : v3) : (q1 ? v0 : v1);
            float s2 = q2 ? (q1 ? v1 : v0) : (q1 ? v3 : v2);
            float s3 = q2 ? (q1 ? v0 : v1) : (q1 ? v2 : v3);
            float g1 = __shfl_xor(s1, 1);
            float g2 = __shfl_xor(s2, 2);
            float g3 = __shfl_xor(s3, 3);
            float fv = q2 ? (q1 ? g3 : g2) : (q1 ? g1 : vq);
            float iv = q2 ? (q1 ? g2 : g3) : (q1 ? vq : g1);
            float ov = q2 ? (q1 ? g1 : vq) : (q1 ? g3 : g2);
            float gv = q2 ? (q1 ? vq : g1) : (q1 ? g2 : g3);
            fv += xv.x * wA0[0] + xv.y * wB0[0] + bb0[0];
            iv += xv.x * wA0[1] + xv.y * wB0[1] + bb0[1];
            ov += xv.x * wA0[2] + xv.y * wB0[2] + bb0[2];
            gv += xv.x * wA0[3] + xv.y * wB0[3] + bb0[3];
            c1a = sigm(fv) * cst0 + sigm(iv) * tanh_fast(gv);
            h1a = sigm(ov) * tanh_fast(c1a);
            cst0 = c1a;
        }
        // ---- tile 1 ----
        float h1b, c1b;
        {
            float v0 = acc1[0], v1 = acc1[1], v2 = acc1[2], v3 = acc1[3];
            float vq = q2 ? (q1 ? v3 : v2) : (q1 ? v1 : v0);
            float s1 = q2 ? (q1 ? v2 : v3) : (q1 ? v0 : v1);
            float s2 = q2 ? (q1 ? v1 : v0) : (q1 ? v3 : v2);
            float s3 = q2 ? (q1 ? v0 : v1) : (q1 ? v2 : v3);
            float g1 = __shfl_xor(s1, 1);
            float g2 = __shfl_xor(s2, 2);
            float g3 = __shfl_xor(s3, 3);
            float fv = q2 ? (q1 ? g3 : g2) : (q1 ? g1 : vq);
            float iv = q2 ? (q1 ? g2 : g3) : (q1 ? vq : g1);
            float ov = q2 ? (q1 ? g1 : vq) : (q1 ? g3 : g2);
            float gv = q2 ? (q1 ? vq : g1) : (q1 ? g2 : g3);
            fv += xv.x * wA1[0] + xv.y * wB1[0] + bb1[0];
            iv += xv.x * wA1[1] + xv.y * wB1[1] + bb1[1];
            ov += xv.x * wA1[2] + xv.y * wB1[2] + bb1[2];
            gv += xv.x * wA1[3] + xv.y * wB1[3] + bb1[3];
            c1b = sigm(fv) * cst1 + sigm(iv) * tanh_fast(gv);
            h1b = sigm(ov) * tanh_fast(c1b);
            cst1 = c1b;
        }

        // ---- pack h,c across cc (per tile) via shuffles ----
        float ha1 = __shfl_xor(h1a, 4), ha2 = __shfl_xor(h1a, 8), ha3 = __shfl_xor(ha1, 8);
        float hb1 = __shfl_xor(h1b, 4), hb2 = __shfl_xor(h1b, 8), hb3 = __shfl_xor(hb1, 8);
        float ca1 = __shfl_xor(c1a, 4), ca2 = __shfl_xor(c1a, 8), ca3 = __shfl_xor(ca1, 8);
        float cb1 = __shfl_xor(c1b, 4), cb2 = __shfl_xor(c1b, 8), cb3 = __shfl_xor(cb1, 8);

        const unsigned tag = (unsigned)(t + 1);
        const int phase = (t + 1) & 1;
        const int hbase0 = slot * HCBLK + wv * 8;      // tile0 col base
        const bool storer = (kb == 0) && (cc == 0);    // lanes 0..3: row = q

        if (t + 1 < TT) {
            // ---- producer: 2 u64 per store-lane, agent relaxed ----
            if (storer) {
                unsigned long long w0 =
                      (unsigned long long)bf16rne(h1a)
                    | ((unsigned long long)bf16rne(ha1) << 16)
                    | ((unsigned long long)bf16rne(ha2) << 32)
                    | ((unsigned long long)bf16rne(ha3) << 48);
                unsigned long long w1 =
                      (unsigned long long)bf16rne(h1b)
                    | ((unsigned long long)bf16rne(hb1) << 16)
                    | ((unsigned long long)bf16rne(hb2) << 32)
                    | ((unsigned long long)bf16rne(hb3) << 48);
                unsigned long long* dst = slab
                    + ((size_t)(phase * 128 + g * SPG + q)) * 128 + (hbase0 >> 2);
                __hip_atomic_store(dst,     w0, __ATOMIC_RELAXED, __HIP_MEMORY_SCOPE_AGENT);
                __hip_atomic_store(dst + 1, w1, __ATOMIC_RELAXED, __HIP_MEMORY_SCOPE_AGENT);
            }
            asm volatile("s_waitcnt vmcnt(0)" ::: "memory");
            __syncthreads();
            if (tid == 0)
                __hip_atomic_store(&flags[(g * SLOTS + slot) * 16], tag,
                                   __ATOMIC_RELAXED, __HIP_MEMORY_SCOPE_AGENT);
        }

        // ---- out flush (overlaps flag propagation) ----
        if (storer) {
            size_t oidx = ((size_t)(g * SPG + q) * TT + t) * HH + hbase0;
            float4 hq0 = {h1a, ha1, ha2, ha3};
            float4 cq0 = {c1a, ca1, ca2, ca3};
            float4 hq1 = {h1b, hb1, hb2, hb3};
            float4 cq1 = {c1b, cb1, cb2, cb3};
            *(float4*)(out + oidx) = hq0;
            *(float4*)(out + oidx + 4) = hq1;
            *(float4*)(out + OSZ + oidx) = cq0;
            *(float4*)(out + OSZ + oidx + 4) = cq1;
        }

        if (t + 1 < TT) {
            xv = *(const float2*)(xp + 2 * (t + 1));   // prefetch x(t+1)

            // ---- all-wave poll of the 8 group flags ----
            {
                long gd = 0;
                for (;;) {
                    unsigned fl = (lane < SLOTS)
                        ? __hip_atomic_load(&flags[(g * SLOTS + lane) * 16],
                                            __ATOMIC_RELAXED, __HIP_MEMORY_SCOPE_AGENT)
                        : tag;
                    if (__all(fl >= tag)) break;
                    __builtin_amdgcn_s_sleep(1);
                    if (++gd > 20000000L) break;   // anti-hang escape
                }
            }

            // ---- refill hsh: 4 rows x 128 u64 = 512 u64, 1 per thread ----
            {
                const unsigned long long* src = slab
                    + ((size_t)(phase * 128 + g * SPG)) * 128;
                unsigned long long d = __hip_atomic_load(src + tid,
                        __ATOMIC_RELAXED, __HIP_MEMORY_SCOPE_AGENT);
                int seq = tid >> 7;                  // 0..3
                int k0  = (tid & 127) << 2;
                *(unsigned long long*)(hsh + seq * 512 + (k0 ^ ((seq & 7) << 3))) = d;
            }
            __syncthreads();
        }
    }
}

extern "C" void kernel_launch(void* const* d_in, const int* in_sizes, int n_in,
                              void* d_out, int out_size, void* d_ws, size_t ws_size,
                              hipStream_t stream) {
    const float* x    = (const float*)d_in[0];
    const float* wih  = (const float*)d_in[1];
    const float* whh  = (const float*)d_in[2];
    const float* bias = (const float*)d_in[3];
    float* out = (float*)d_out;
    float* ws  = (float*)d_ws;

    // zero the flag lines every launch (graph replay safe)
    hipMemsetAsync((char*)d_ws + 256 * 1024, 0, NG * SLOTS * 16 * sizeof(unsigned), stream);

    dim3 grid(NG * SLOTS), block(512);
    hipLaunchKernelGGL(lstm_d8, grid, block, 0, stream, x, wih, whh, bias, out, ws);
}